// Round 13
// baseline (461.098 us; speedup 1.0000x reference)
//
#include <hip/hip_runtime.h>
#include <hip/hip_bf16.h>
#include <math.h>

#define NN 50000
#define NE 800000
#define FF 64
#define ZD 192

typedef __attribute__((ext_vector_type(8))) short bf16x8;
typedef __attribute__((ext_vector_type(4))) float f32x4;

__device__ __forceinline__ short f2bs(float f){
  union { __hip_bfloat16 h; short s; } u; u.h = __float2bfloat16(f); return u.s;
}
__device__ __forceinline__ unsigned packbf(float a, float b){
  return ((unsigned)(unsigned short)f2bs(b) << 16) | (unsigned)(unsigned short)f2bs(a);
}
__device__ __forceinline__ float lo16f(unsigned u){ union{unsigned u; float f;} v; v.u = u << 16; return v.f; }
__device__ __forceinline__ float hi16f(unsigned u){ union{unsigned u; float f;} v; v.u = u & 0xFFFF0000u; return v.f; }
__device__ __forceinline__ float sigm(float x){ return 1.0f/(1.0f+__expf(-x)); }
__device__ __forceinline__ float sofp(float x){ return fmaxf(x,0.0f)+__logf(1.0f+__expf(-fabsf(x))); }
__device__ __forceinline__ float fsilu(float x){ return x/(1.0f+__expf(-x)); }

// ---------------------------------------------------------------------------
// k1: aout=atom copy + per-node gating-linear parts via MFMA (packed bf16).
// ---------------------------------------------------------------------------
__global__ __launch_bounds__(256) void k1_node_pre(
    const float* __restrict__ atom,
    const float* __restrict__ wf, const float* __restrict__ ws,
    unsigned* __restrict__ P2u, float* __restrict__ aout)
{
  int tid0 = blockIdx.x * 256 + threadIdx.x;
  int nthr = gridDim.x * 256;
  const float4* a4 = (const float4*)atom;
  float4* o4 = (float4*)aout;
  for (int i = tid0; i < NN*FF/4; i += nthr) o4[i] = a4[i];

  int lane = threadIdx.x & 63;
  int c = lane & 15, kb = lane >> 4;
  int wid = blockIdx.x * 4 + (threadIdx.x >> 6);
  int nw = gridDim.x * 4;
  for (int g = wid; g < NN/16; g += nw) {
    int n0 = g * 16;
    const float* arow = &atom[(size_t)(n0 + c) * FF + kb*8];
    bf16x8 A0, A1;
    #pragma unroll
    for (int j = 0; j < 8; j++) { A0[j] = f2bs(arow[j]); A1[j] = f2bs(arow[32+j]); }
    f32x4 acc[16];
    #pragma unroll
    for (int t = 0; t < 16; t++) acc[t] = (f32x4){0,0,0,0};
    #pragma unroll
    for (int t = 0; t < 16; t++) {
      int og = t*16 + c;
      const float* src;
      if (t < 4)       src = &wf[og*ZD];
      else if (t < 8)  src = &wf[(og-64)*ZD + 64];
      else if (t < 12) src = &ws[(og-128)*ZD];
      else             src = &ws[(og-192)*ZD + 64];
      bf16x8 B0, B1;
      #pragma unroll
      for (int j = 0; j < 8; j++) { B0[j] = f2bs(src[kb*8+j]); B1[j] = f2bs(src[32+kb*8+j]); }
      acc[t] = __builtin_amdgcn_mfma_f32_16x16x32_bf16(A0, B0, acc[t], 0,0,0);
      acc[t] = __builtin_amdgcn_mfma_f32_16x16x32_bf16(A1, B1, acc[t], 0,0,0);
    }
    #pragma unroll
    for (int t = 0; t < 8; t++) {
      #pragma unroll
      for (int r = 0; r < 4; r++) {
        int n = n0 + kb*4 + r;
        P2u[(size_t)n*128 + t*16 + c] = packbf(acc[t][r], acc[t+8][r]);
      }
    }
  }
}

// ---------------------------------------------------------------------------
// k2: depth-2 software pipeline with store-decoupled vmcnt schedule.
//  Per-iter issue order:
//    MFMA(g) -> [wait streams(g+1); drains gathers(g), both 1 iter old]
//    -> cvt/shuffles(g+1) -> stash(g) -> epilogue+atomics(g)
//    -> issue gathers(g+1) -> issue streams(g+2)
//  Invariant: every consume-wait targets loads issued a full iteration
//  earlier; stores/atomics always sit YOUNGER in the vmcnt FIFO than the
//  next wait's target, so their ack latency never blocks an iteration.
// ---------------------------------------------------------------------------
__global__ __launch_bounds__(256) void k2_msg(
    const int* __restrict__ eidx, const float* __restrict__ efea,
    const float* __restrict__ dist,
    const float* __restrict__ wf, const float* __restrict__ ws,
    const float* __restrict__ bfb, const float* __restrict__ bsb,
    const float* __restrict__ fc1w,
    const unsigned* __restrict__ P2u, float* __restrict__ aout,
    float* __restrict__ eout)
{
  int tid = threadIdx.x;
  int lane = tid & 63;
  int lw = tid >> 6;
  int c = lane & 15, kb = lane >> 4;

  bf16x8 Bf[9][2];
  #pragma unroll
  for (int t = 0; t < 9; t++) {
    int og = t*16 + c;
    const float* src = nullptr;
    if (t < 4)            src = &wf[og*ZD + 128];
    else if (t < 8)       src = &ws[(og-64)*ZD + 128];
    else if (og-128 < 14) src = &fc1w[(og-128)*ZD + 128];
    #pragma unroll
    for (int f = 0; f < 2; f++) {
      bf16x8 r;
      #pragma unroll
      for (int j = 0; j < 8; j++) r[j] = src ? f2bs(src[f*32 + kb*8 + j]) : (short)0;
      Bf[t][f] = r;
    }
  }
  float bfo[4], bso[4];
  #pragma unroll
  for (int t = 0; t < 4; t++) { bfo[t] = bfb[t*16+c]; bso[t] = bsb[t*16+c]; }

  const int ngroups = NE/16;
  int wid = blockIdx.x*4 + lw;
  int nw = gridDim.x*4;
  if (wid >= ngroups) return;

  // ---- prologue: streams(g0) -> A/meta(g0); issue gathers(g0); streams(g1)
  int g = wid;
  {
  }
  int pS, pD; float pDe; float4 pe0, pe1, pe2, pe3;
  {
    int e0 = g*16;
    pS  = eidx[e0 + c];
    pD  = eidx[NE + e0 + c];
    pDe = dist[e0 + c];
    const float4* er = (const float4*)&efea[(size_t)(e0 + c)*FF];
    pe0 = er[kb*2]; pe1 = er[kb*2+1]; pe2 = er[8+kb*2]; pe3 = er[8+kb*2+1];
  }
  bf16x8 A0, A1;
  A0[0]=f2bs(pe0.x); A0[1]=f2bs(pe0.y); A0[2]=f2bs(pe0.z); A0[3]=f2bs(pe0.w);
  A0[4]=f2bs(pe1.x); A0[5]=f2bs(pe1.y); A0[6]=f2bs(pe1.z); A0[7]=f2bs(pe1.w);
  A1[0]=f2bs(pe2.x); A1[1]=f2bs(pe2.y); A1[2]=f2bs(pe2.z); A1[3]=f2bs(pe2.w);
  A1[4]=f2bs(pe3.x); A1[5]=f2bs(pe3.y); A1[6]=f2bs(pe3.z); A1[7]=f2bs(pe3.w);
  int sN[4], dN[4]; float wd[4];
  {
    float wdv = __expf(-pDe*pDe*(1.0f/18.0f));
    #pragma unroll
    for (int r = 0; r < 4; r++) {
      sN[r] = __shfl(pS, kb*4 + r, 64);
      dN[r] = __shfl(pD, kb*4 + r, 64);
      wd[r] = __shfl(wdv, kb*4 + r, 64);
    }
  }
  // issue gathers(g0)
  unsigned vdu[4][4], vsu[4][4];
  #pragma unroll
  for (int r = 0; r < 4; r++) {
    #pragma unroll
    for (int t = 0; t < 4; t++) {
      vdu[r][t] = P2u[(size_t)dN[r]*128 + t*16 + c];
      vsu[r][t] = P2u[(size_t)sN[r]*128 + 64 + t*16 + c];
    }
  }
  // issue streams(g1)
  {
    int gn = g + nw; if (gn >= ngroups) gn = g;
    int e0n = gn*16;
    pS  = eidx[e0n + c];
    pD  = eidx[NE + e0n + c];
    pDe = dist[e0n + c];
    const float4* er = (const float4*)&efea[(size_t)(e0n + c)*FF];
    pe0 = er[kb*2]; pe1 = er[kb*2+1]; pe2 = er[8+kb*2]; pe3 = er[8+kb*2+1];
  }

  for (;;) {
    int e0 = g*16;
    // 1. MFMA(g)  (A,B in regs -> no memory wait)
    f32x4 acc[9];
    #pragma unroll
    for (int t = 0; t < 9; t++) acc[t] = (f32x4){0,0,0,0};
    #pragma unroll
    for (int t = 0; t < 9; t++) {
      acc[t] = __builtin_amdgcn_mfma_f32_16x16x32_bf16(A0, Bf[t][0], acc[t], 0,0,0);
      acc[t] = __builtin_amdgcn_mfma_f32_16x16x32_bf16(A1, Bf[t][1], acc[t], 0,0,0);
    }
    // 2. consume streams(g+1): wait (drains gathers(g) too); cvt + shuffles
    bf16x8 nA0, nA1;
    nA0[0]=f2bs(pe0.x); nA0[1]=f2bs(pe0.y); nA0[2]=f2bs(pe0.z); nA0[3]=f2bs(pe0.w);
    nA0[4]=f2bs(pe1.x); nA0[5]=f2bs(pe1.y); nA0[6]=f2bs(pe1.z); nA0[7]=f2bs(pe1.w);
    nA1[0]=f2bs(pe2.x); nA1[1]=f2bs(pe2.y); nA1[2]=f2bs(pe2.z); nA1[3]=f2bs(pe2.w);
    nA1[4]=f2bs(pe3.x); nA1[5]=f2bs(pe3.y); nA1[6]=f2bs(pe3.z); nA1[7]=f2bs(pe3.w);
    int nsN[4], ndN[4]; float nwd[4];
    {
      float wdv = __expf(-pDe*pDe*(1.0f/18.0f));
      #pragma unroll
      for (int r = 0; r < 4; r++) {
        nsN[r] = __shfl(pS, kb*4 + r, 64);
        ndN[r] = __shfl(pD, kb*4 + r, 64);
        nwd[r] = __shfl(wdv, kb*4 + r, 64);
      }
    }
    // 3. stash(g)
    if (c < 14) {
      #pragma unroll
      for (int r = 0; r < 4; r++)
        eout[(size_t)(e0 + kb*4 + r)*FF + c] = acc[8][r];
    }
    // 4. epilogue(g) + atomics (gather data already drained by step 2's wait)
    #pragma unroll
    for (int r = 0; r < 4; r++) {
      #pragma unroll
      for (int t = 0; t < 4; t++) {
        float zf = acc[t][r]   + lo16f(vdu[r][t]) + lo16f(vsu[r][t]) + bfo[t];
        float zs = acc[t+4][r] + hi16f(vdu[r][t]) + hi16f(vsu[r][t]) + bso[t];
        float m = sigm(zf) * sofp(zs) * wd[r];
        atomicAdd(&aout[(size_t)dN[r]*FF + t*16 + c], m);
      }
    }
    // advance
    g += nw;
    if (g >= ngroups) break;
    A0 = nA0; A1 = nA1;
    #pragma unroll
    for (int r = 0; r < 4; r++) { sN[r] = nsN[r]; dN[r] = ndN[r]; wd[r] = nwd[r]; }
    // 5. issue gathers(g)  (regs free: epilogue consumed old vdu/vsu)
    #pragma unroll
    for (int r = 0; r < 4; r++) {
      #pragma unroll
      for (int t = 0; t < 4; t++) {
        vdu[r][t] = P2u[(size_t)dN[r]*128 + t*16 + c];
        vsu[r][t] = P2u[(size_t)sN[r]*128 + 64 + t*16 + c];
      }
    }
    // 6. issue streams(g+1)
    {
      int gn = g + nw; if (gn >= ngroups) gn = g;
      int e0n = gn*16;
      pS  = eidx[e0n + c];
      pD  = eidx[NE + e0n + c];
      pDe = dist[e0n + c];
      const float4* er = (const float4*)&efea[(size_t)(e0n + c)*FF];
      pe0 = er[kb*2]; pe1 = er[kb*2+1]; pe2 = er[8+kb*2]; pe3 = er[8+kb*2+1];
    }
  }
}

// ---------------------------------------------------------------------------
// k3: per-node fc1 partials on UPDATED node features.
// ---------------------------------------------------------------------------
__global__ __launch_bounds__(256) void k3_cpre(
    const float* __restrict__ aout, const float* __restrict__ fc1w,
    float* __restrict__ C)
{
  __shared__ float wT[64*32];
  __shared__ float xs[4][64];
  int tid = threadIdx.x;
  for (int i = tid; i < 64*28; i += 256) {
    int k = i / 28, j = i % 28;
    wT[k*32 + j] = (j < 14) ? fc1w[j*ZD + k] : fc1w[(j-14)*ZD + 64 + k];
  }
  __syncthreads();
  int o  = tid & 63;
  int lw = tid >> 6;
  int wid = blockIdx.x * 4 + lw;
  int nw  = gridDim.x * 4;
  for (int n = wid; n < NN; n += nw) {
    xs[lw][o] = aout[(size_t)n*FF + o];
    float acc = 0.f;
    if (o < 28) {
      for (int k = 0; k < 64; k++) acc += xs[lw][k] * wT[k*32 + o];
      C[n*28 + o] = acc;
    }
  }
}

// ---------------------------------------------------------------------------
// k5: edge-update MLP. 8 edges/wave. h-edge-part read from eout stash.
// ---------------------------------------------------------------------------
__global__ __launch_bounds__(256) void k5_edge_mlp(
    const int* __restrict__ eidx,
    const float* __restrict__ fc1b,
    const float* __restrict__ fc2w, const float* __restrict__ fc2b,
    const float* __restrict__ C, float* __restrict__ eout)
{
  __shared__ float w2T[14*64];
  __shared__ float hs[4][128];
  int tid = threadIdx.x;
  for (int i = tid; i < 14*64; i += 256) {
    int j = i >> 6, o = i & 63;
    w2T[i] = fc2w[o*14 + j];
  }
  __syncthreads();
  int o  = tid & 63;
  int lw = tid >> 6;
  int j4 = o >> 2, q = o & 3;
  int wid = blockIdx.x*4 + lw;
  int nw  = gridDim.x*4;
  for (int g = wid; g < NE/8; g += nw) {
    int e0 = g*8;
    #pragma unroll
    for (int pass = 0; pass < 2; pass++) {
      int ee = pass*4 + q;
      int e = e0 + ee;
      if (j4 < 14) {
        int sN = eidx[e], dN = eidx[NE+e];
        float h = eout[(size_t)e*FF + j4] + C[sN*28 + j4] + C[dN*28 + 14 + j4] + fc1b[j4];
        hs[lw][ee*16 + j4] = fsilu(h);
      }
    }
    asm volatile("s_waitcnt lgkmcnt(0)" ::: "memory");  // in-wave LDS RAW
    float b2 = fc2b[o];
    #pragma unroll
    for (int ee = 0; ee < 8; ee++) {
      float acc = b2;
      #pragma unroll
      for (int jj = 0; jj < 14; jj++)
        acc += w2T[jj*64 + o] * hs[lw][ee*16 + jj];
      eout[(size_t)(e0 + ee)*FF + o] = fsilu(acc);
    }
  }
}

// ---------------------------------------------------------------------------
extern "C" void kernel_launch(void* const* d_in, const int* in_sizes, int n_in,
                              void* d_out, int out_size, void* d_ws, size_t ws_size,
                              hipStream_t stream) {
  const float* atom  = (const float*)d_in[0];
  const int*   eidx  = (const int*)  d_in[1];
  const float* efea  = (const float*)d_in[2];
  const float* dist  = (const float*)d_in[4];
  const float* wf    = (const float*)d_in[6];
  const float* bf    = (const float*)d_in[7];
  const float* ws    = (const float*)d_in[8];
  const float* bs    = (const float*)d_in[9];
  const float* fc1w  = (const float*)d_in[10];
  const float* fc1b  = (const float*)d_in[11];
  const float* fc2w  = (const float*)d_in[12];
  const float* fc2b  = (const float*)d_in[13];

  float* aout = (float*)d_out;                 // [50000, 64]
  float* eout = aout + (size_t)NN * FF;        // [800000, 64]

  unsigned* P2u = (unsigned*)d_ws;                              // 25.6 MB
  float*    C   = (float*)((char*)d_ws + (size_t)NN * 128 * 4); // +5.6 MB

  hipLaunchKernelGGL(k1_node_pre, dim3(512), dim3(256), 0, stream,
                     atom, wf, ws, P2u, aout);
  hipLaunchKernelGGL(k2_msg, dim3(2048), dim3(256), 0, stream,
                     eidx, efea, dist, wf, ws, bf, bs, fc1w, P2u, aout, eout);
  hipLaunchKernelGGL(k3_cpre, dim3(512), dim3(256), 0, stream,
                     aout, fc1w, C);
  hipLaunchKernelGGL(k5_edge_mlp, dim3(2048), dim3(256), 0, stream,
                     eidx, fc1b, fc2w, fc2b, C, eout);
}